// Round 8
// baseline (189.778 us; speedup 1.0000x reference)
//
#include <hip/hip_runtime.h>
#include <cstdint>
#include <cstddef>

typedef int int4v __attribute__((ext_vector_type(4)));
typedef signed char schar;

#define DEVI __device__ __forceinline__

DEVI void load_lds16(const void* g, void* l) {
  __builtin_amdgcn_global_load_lds(
      (const __attribute__((address_space(1))) void*)g,
      (__attribute__((address_space(3))) void*)l, 16, 0, 0);
}

// Bare advisory waits (no sched_barrier, no memory clobber). Correctness of
// ds_read->MFMA register deps is guaranteed by compiler-inserted waits; these
// only shape the schedule.
#define BAR() __builtin_amdgcn_s_barrier()
#define LGKM(n) asm volatile("s_waitcnt lgkmcnt(" #n ")")
#define VMW(n) asm volatile("s_waitcnt vmcnt(" #n ")")

// ---- pack int32 -> int8, linear (4 elems/thread) ----
__global__ __launch_bounds__(256) void pack_i8(const int* __restrict__ src,
                                               signed char* __restrict__ dst,
                                               int n4) {
  int i = blockIdx.x * 256 + threadIdx.x;
  if (i >= n4) return;
  int4v v = ((const int4v*)src)[i];
  int p = (v.x & 255) | ((v.y & 255) << 8) | ((v.z & 255) << 16) | (v.w << 24);
  ((int*)dst)[i] = p;
}

// ---- pack + transpose: w[K][N] int32 -> wT[N][K] int8, 64x64 LDS tiles ----
__global__ __launch_bounds__(256) void pack_wT(const int* __restrict__ w,
                                               signed char* __restrict__ wT,
                                               int K, int N) {
  __shared__ signed char t[64][68];
  int n0 = blockIdx.x * 64, k0 = blockIdx.y * 64;
  int tr = threadIdx.x >> 6, tc = threadIdx.x & 63;
#pragma unroll
  for (int i = 0; i < 16; ++i) {
    int r = i * 4 + tr;
    t[r][tc] = (signed char)w[(size_t)(k0 + r) * N + n0 + tc];
  }
  __syncthreads();
#pragma unroll
  for (int i = 0; i < 16; ++i) {
    int r = i * 4 + tr;
    wT[(size_t)(n0 + r) * K + k0 + tc] = t[tc][r];
  }
}

// ---- 256x256 intra-wave-pipelined i8 GEMM: C = A[M,K] * BT[N,K]^T ----
// 8 waves (2Mx4N), 128x64 out/wave, acc[8][4] = 128 AGPR.
// BK=64 B (one 16x16x64 K-step/tile). FOUR LDS buffers (4 x 32 KB).
// Intra-wave pipeline: A-frags for tile T+1 are ds_read during tile T
// (P2/P3) into the alternate register set; B-frags read JIT (2+2 reads).
// Staging 3 tiles ahead: stage(T+3) issued at P0; end-of-tile vmcnt(4)
// retires stage(T+2) (issued ~2 tiles back => free) leaving T+3 in flight.
// Sync per tile: 2x lgkm(0) (fresh 2-read drains), 1x vmcnt(4), 1 barrier.
// Safety: buf[X] written >=2 barriers after its previous reads drained;
// read >=1 barrier after all waves retired its staging (vmcnt(4) chain).
template <int EPI>
__global__ __launch_bounds__(512, 2) void gemmW(
    const schar* __restrict__ A, const schar* __restrict__ BT,
    int M, int N, int K, const int* __restrict__ bias_i,
    const float* __restrict__ alphaP, const float* __restrict__ betaP,
    const float* __restrict__ bias_f, schar* __restrict__ outQ,
    float* __restrict__ outF) {
  extern __shared__ schar lds[];

  const int tid = threadIdx.x;
  const int wid = tid >> 6, lane = tid & 63;
  const int wr = wid >> 2, wc = wid & 3;  // 2M x 4N waves
  const int l16 = lane & 15, l4 = lane >> 4;

  // XCD-bijective block swizzle (nwg % 8 == 0 for both GEMMs)
  const int gx = gridDim.x;
  const int nwg = gx * gridDim.y;
  const int bid = blockIdx.y * gx + blockIdx.x;
  const int swz = (bid & 7) * (nwg >> 3) + (bid >> 3);
  const int rowBase = (swz / gx) * 256;
  const int colBase = (swz % gx) * 256;
  const int NT = K >> 6;  // 64-B K-tiles (NT is even: K=1024 or 4096)

  // pin scalar params; drain SMEM before advisory counted waits
  const float alpha = alphaP[0];
  const float beta = (EPI == 0) ? betaP[0] : 0.f;
  asm volatile("" ::"s"(alpha), "s"(beta));
  LGKM(0);

  // staging source pointers (pre-swizzled global slot; LDS dest linear).
  const schar* gA[2];
  const schar* gB[2];
#pragma unroll
  for (int c = 0; c < 2; ++c) {
    int o = c * 8192 + tid * 16;
    int r = o >> 6;  // row 0..255 (64-B rows)
    int g = ((o >> 4) & 3) ^ ((r >> 1) & 3);
    gA[c] = A + (size_t)(rowBase + r) * K + g * 16;
    gB[c] = BT + (size_t)(colBase + r) * K + g * 16;
  }

  auto stage = [&](int buf, int t) {
    schar* d = lds + buf * 32768 + wid * 1024;
    load_lds16(gA[0] + (size_t)t * 64, d);
    load_lds16(gA[1] + (size_t)t * 64, d + 8192);
    load_lds16(gB[0] + (size_t)t * 64, d + 16384);
    load_lds16(gB[1] + (size_t)t * 64, d + 24576);
  };

  // fragment read offset within a row: slot = l4 ^ ((l16>>1)&3)
  // (frag row bases are multiples of 16 => (row>>1)&3 == (l16>>1)&3)
  const int slotc = (l4 ^ ((l16 >> 1) & 3)) * 16 + l16 * 64;
  const int aoff = wr * 8192 + slotc;   // + f*1024, f=0..7
  const int boff = 16384 + wc * 4096 + slotc;  // + n*1024, n=0..3

  int4v acc[8][4] = {};
  int4v aA0[4], aB0[4], aA1[4], aB1[4];  // A frags, double-buffered by tile
  int4v b0[2], b1[2];

#define RD_AH(DST, Ab)                                            \
  _Pragma("unroll") for (int f = 0; f < 4; ++f) (DST)[f] =        \
      *(const int4v*)((Ab) + aoff + f * 1024)
#define RD_AL(DST, Ab)                                            \
  _Pragma("unroll") for (int f = 0; f < 4; ++f) (DST)[f] =        \
      *(const int4v*)((Ab) + aoff + (4 + f) * 1024)
#define RD_B(DST, Bb, N0)                                         \
  _Pragma("unroll") for (int n = 0; n < 2; ++n) (DST)[n] =        \
      *(const int4v*)((Bb) + boff + ((N0) + n) * 1024)
#define QUAD(AF, M0, BF, N0)                                           \
  do {                                                                 \
    __builtin_amdgcn_s_setprio(1);                                     \
    _Pragma("unroll") for (int mi = 0; mi < 4; ++mi)                   \
        _Pragma("unroll") for (int ni = 0; ni < 2; ++ni)               \
            acc[(M0) + mi][(N0) + ni] =                                \
        __builtin_amdgcn_mfma_i32_16x16x64_i8(                         \
            (AF)[mi], (BF)[ni], acc[(M0) + mi][(N0) + ni], 0, 0, 0);   \
    __builtin_amdgcn_s_setprio(0);                                     \
  } while (0)

  // One tile body. CUR = this tile's A regs, NXT = next tile's A regs.
#define TILE(T, cA, cB, nA, nB)                                        \
  do {                                                                 \
    const int tt = (T);                                                \
    const schar* buf = lds + (tt & 3) * 32768;                         \
    const schar* bufn = lds + ((tt + 1) & 3) * 32768;                  \
    /* P0: stage 3 ahead; JIT b0; Q00 */                               \
    if (tt + 3 < NT) stage((tt + 3) & 3, tt + 3);                      \
    RD_B(b0, buf, 0);                                                  \
    LGKM(0);                                                           \
    QUAD(cA, 0, b0, 0);                                                \
    /* P1: JIT b1; Q10 */                                              \
    RD_B(b1, buf, 2);                                                  \
    LGKM(0);                                                           \
    QUAD(cB, 4, b0, 0);                                                \
    /* P2: lookahead A-high of T+1; Q01 (b1 drained by P1 wait) */     \
    if (tt + 1 < NT) RD_AH(nA, bufn);                                  \
    QUAD(cA, 0, b1, 2);                                                \
    /* P3: lookahead A-low of T+1; Q11 */                              \
    if (tt + 1 < NT) RD_AL(nB, bufn);                                  \
    QUAD(cB, 4, b1, 2);                                                \
    if (tt + 3 < NT) {                                                 \
      VMW(4); /* stage(T+2) retired; stage(T+3) stays in flight */     \
    } else {                                                           \
      VMW(0); /* tail drain (last 3 tiles) */                          \
    }                                                                  \
    BAR();                                                             \
  } while (0)

  // prologue: stage tiles 0..2; wait tile 0 (1,2 float); pre-read A(0)
  stage(0, 0);
  stage(1, 1);
  stage(2, 2);
  VMW(8);
  BAR();
  RD_AH(aA0, lds);
  RD_AL(aB0, lds);

  for (int T = 0; T < NT; T += 2) {
    TILE(T, aA0, aB0, aA1, aB1);
    TILE(T + 1, aA1, aB1, aA0, aB0);
  }

  // ---- epilogue; C/D frag: col = lane&15, row = (lane>>4)*4 + j ----
  if (EPI == 0) {
#pragma unroll
    for (int MI = 0; MI < 8; ++MI) {
      int row = rowBase + wr * 128 + MI * 16 + l4 * 4;
#pragma unroll
      for (int NI = 0; NI < 4; ++NI) {
        int col = colBase + wc * 64 + NI * 16 + l16;
        float bt = (float)bias_i[col] * beta;
#pragma unroll
        for (int j = 0; j < 4; ++j) {
          float h = (float)acc[MI][NI][j] * alpha + bt;
          h = fmaxf(h, 0.f);
          h = rintf(h);  // numpy round-half-even
          h = fminf(h, 127.f);
          outQ[(size_t)(row + j) * N + col] = (schar)h;
        }
      }
    }
  } else {
#pragma unroll
    for (int MI = 0; MI < 8; ++MI) {
      int row = rowBase + wr * 128 + MI * 16 + l4 * 4;
#pragma unroll
      for (int NI = 0; NI < 4; ++NI) {
        int col = colBase + wc * 64 + NI * 16 + l16;
        float bv = bias_f[col];
#pragma unroll
        for (int j = 0; j < 4; ++j)
          outF[(size_t)(row + j) * N + col] =
              (float)acc[MI][NI][j] * alpha + bv;
      }
    }
  }
#undef RD_AH
#undef RD_AL
#undef RD_B
#undef QUAD
#undef TILE
}

extern "C" void kernel_launch(void* const* d_in, const int* in_sizes, int n_in,
                              void* d_out, int out_size, void* d_ws,
                              size_t ws_size, hipStream_t stream) {
  const int M = 16384, H = 1024, I = 4096;  // B*S = 16384
  const int* hidden = (const int*)d_in[0];
  const int* w_fc = (const int*)d_in[1];
  const int* b_fc = (const int*)d_in[2];
  const float* alpha_fc = (const float*)d_in[3];
  const float* beta_fc = (const float*)d_in[4];
  const int* w_proj = (const int*)d_in[5];
  const float* b_proj = (const float*)d_in[6];
  const float* alpha_proj = (const float*)d_in[7];
  float* out = (float*)d_out;

  signed char* hq = (signed char*)d_ws;     // [M][I]  64 MB
  signed char* aP = hq + (size_t)M * I;     // [M][H]  16 MB
  signed char* wfcT = aP + (size_t)M * H;   // [I][H]   4 MB (w_fc^T)
  signed char* wpT = wfcT + (size_t)I * H;  // [H][I]   4 MB (w_proj^T)

  hipFuncSetAttribute((const void*)gemmW<0>,
                      hipFuncAttributeMaxDynamicSharedMemorySize, 131072);
  hipFuncSetAttribute((const void*)gemmW<1>,
                      hipFuncAttributeMaxDynamicSharedMemorySize, 131072);

  pack_i8<<<(M * H / 4 + 255) / 256, 256, 0, stream>>>(hidden, aP, M * H / 4);
  pack_wT<<<dim3(I / 64, H / 64), 256, 0, stream>>>(w_fc, wfcT, H, I);
  pack_wT<<<dim3(H / 64, I / 64), 256, 0, stream>>>(w_proj, wpT, I, H);

  gemmW<0><<<dim3(I / 256, M / 256), 512, 131072, stream>>>(
      aP, wfcT, M, I, H, b_fc, alpha_fc, beta_fc, nullptr, hq, nullptr);
  gemmW<1><<<dim3(H / 256, M / 256), 512, 131072, stream>>>(
      hq, wpT, M, H, I, nullptr, alpha_proj, nullptr, b_proj, nullptr, out);
}